// Round 1
// baseline (194.829 us; speedup 1.0000x reference)
//
#include <hip/hip_runtime.h>

#define Bn  4
#define Cn  64
#define Hn  96
#define Wn  96
#define Con 64
#define Kk  9
#define HW  (Hn*Wn)     // 9216
#define PIX 16          // pixels per block (96 % 16 == 0 -> no row crossing)
#define CK  (Cn*Kk)     // 576
#define NTILE (HW/PIX)  // 576

__global__ __launch_bounds__(256) void dcnv2_fused(
    const float* __restrict__ input,   // [B, C, H, W]
    const float* __restrict__ offset,  // [B, 2K, H, W]  ch 2k = dy, 2k+1 = dx
    const float* __restrict__ mask,    // [B, K, H, W]
    const float* __restrict__ weight,  // [Co, C, 3, 3]
    const float* __restrict__ bias,    // [Co]
    float* __restrict__ out)           // [B, Co, Ho, Wo]
{
    __shared__ float s_w[PIX*Kk][4];   // bilinear weights (mask+validity folded)
    __shared__ int   s_a[PIX*Kk][4];   // clamped gather addresses within image plane
    __shared__ float s_samp[CK*PIX];   // samp[ck][p], ck = c*9+k

    const int t    = threadIdx.x;
    const int blk  = blockIdx.x;
    const int b    = blk / NTILE;
    const int tile = blk % NTILE;
    const int pix0 = tile * PIX;
    const int ho   = pix0 / Wn;
    const int wo0  = pix0 % Wn;

    // ---- phase 0: per-(pixel,k) bilinear params ----
    if (t < PIX*Kk) {
        const int p  = t / Kk;
        const int k  = t - p*Kk;
        const int wo = wo0 + p;
        const int sp = ho*Wn + wo;
        const float dy = offset[(size_t)(b*2*Kk + 2*k    )*HW + sp];
        const float dx = offset[(size_t)(b*2*Kk + 2*k + 1)*HW + sp];
        const float m  = mask  [(size_t)(b*Kk + k)*HW + sp];
        const float py = dy + (float)(k/3) + (float)(ho - 1);
        const float px = dx + (float)(k%3) + (float)(wo - 1);
        const float fy = floorf(py), fx = floorf(px);
        const int iy0 = (int)fy, ix0 = (int)fx;
        const int iy1 = iy0 + 1, ix1 = ix0 + 1;
        const float wy = py - fy, wx = px - fx;
        const float vy0 = (iy0 >= 0 && iy0 < Hn) ? 1.f : 0.f;
        const float vy1 = (iy1 >= 0 && iy1 < Hn) ? 1.f : 0.f;
        const float vx0 = (ix0 >= 0 && ix0 < Wn) ? 1.f : 0.f;
        const float vx1 = (ix1 >= 0 && ix1 < Wn) ? 1.f : 0.f;
        const int cy0 = min(max(iy0,0),Hn-1), cy1 = min(max(iy1,0),Hn-1);
        const int cx0 = min(max(ix0,0),Wn-1), cx1 = min(max(ix1,0),Wn-1);
        s_w[t][0] = m*(1.f-wy)*(1.f-wx)*vy0*vx0;
        s_w[t][1] = m*(1.f-wy)*wx      *vy0*vx1;
        s_w[t][2] = m*wy      *(1.f-wx)*vy1*vx0;
        s_w[t][3] = m*wy      *wx      *vy1*vx1;
        s_a[t][0] = cy0*Wn+cx0;
        s_a[t][1] = cy0*Wn+cx1;
        s_a[t][2] = cy1*Wn+cx0;
        s_a[t][3] = cy1*Wn+cx1;
    }
    __syncthreads();

    // ---- phase 1: build samp[ck][p] in LDS ----
    {
        const float* __restrict__ inb = input + (size_t)b*Cn*HW;
        #pragma unroll 4
        for (int e = t; e < CK*PIX; e += 256) {
            const int ck = e >> 4;       // / PIX
            const int p  = e & 15;
            const int c  = ck / 9;
            const int k  = ck - c*9;
            const int pk = p*Kk + k;
            const float* __restrict__ ic = inb + (size_t)c*HW;
            const float v = s_w[pk][0]*ic[s_a[pk][0]]
                          + s_w[pk][1]*ic[s_a[pk][1]]
                          + s_w[pk][2]*ic[s_a[pk][2]]
                          + s_w[pk][3]*ic[s_a[pk][3]];
            s_samp[ck*PIX + p] = v;
        }
    }
    __syncthreads();

    // ---- phase 2: out[o, p] = sum_ck W[o,ck] * samp[ck,p] ----
    const int o  = t & 63;
    const int pg = t >> 6;          // 0..3, pixels pg*4 .. pg*4+3
    const float4* __restrict__ wrow = (const float4*)(weight + (size_t)o*CK);
    float ax = 0.f, ay = 0.f, az = 0.f, aw = 0.f;
    #pragma unroll 4
    for (int q = 0; q < CK/4; ++q) {
        const float4 wv = wrow[q];
        const float4 s0 = *(const float4*)&s_samp[(4*q+0)*PIX + pg*4];
        const float4 s1 = *(const float4*)&s_samp[(4*q+1)*PIX + pg*4];
        const float4 s2 = *(const float4*)&s_samp[(4*q+2)*PIX + pg*4];
        const float4 s3 = *(const float4*)&s_samp[(4*q+3)*PIX + pg*4];
        ax += wv.x*s0.x + wv.y*s1.x + wv.z*s2.x + wv.w*s3.x;
        ay += wv.x*s0.y + wv.y*s1.y + wv.z*s2.y + wv.w*s3.y;
        az += wv.x*s0.z + wv.y*s1.z + wv.z*s2.z + wv.w*s3.z;
        aw += wv.x*s0.w + wv.y*s1.w + wv.z*s2.w + wv.w*s3.w;
    }
    const float bo = bias[o];
    float* __restrict__ op = out + (size_t)(b*Con + o)*HW + pix0 + pg*4;
    op[0] = ax + bo;
    op[1] = ay + bo;
    op[2] = az + bo;
    op[3] = aw + bo;
}

extern "C" void kernel_launch(void* const* d_in, const int* in_sizes, int n_in,
                              void* d_out, int out_size, void* d_ws, size_t ws_size,
                              hipStream_t stream) {
    const float* input  = (const float*)d_in[0];
    const float* offset = (const float*)d_in[1];
    const float* mask   = (const float*)d_in[2];
    const float* weight = (const float*)d_in[3];
    const float* bias   = (const float*)d_in[4];
    float* out = (float*)d_out;
    dim3 grid(Bn * NTILE);
    dim3 block(256);
    hipLaunchKernelGGL(dcnv2_fused, grid, block, 0, stream,
                       input, offset, mask, weight, bias, out);
}

// Round 2
// 45.555 us; speedup vs baseline: 4.2768x; 4.2768x over previous
//
#include <hip/hip_runtime.h>

#define Bn  4
#define Cn  64
#define Hn  96
#define Wn  96
#define Con 64
#define Kk  9
#define HW  (Hn*Wn)     // 9216
#define PIX 16
#define CK  (Cn*Kk)     // 576
#define NTILE (HW/PIX)  // 576
#define SROW 584        // samp row stride in bf16 elems (1168 B, 16B-aligned, bank-optimal)

typedef __attribute__((ext_vector_type(8))) short bf16x8;
typedef __attribute__((ext_vector_type(4))) float f32x4;

static __device__ __forceinline__ float bf2f(ushort u) {
    return __uint_as_float(((unsigned int)u) << 16);
}
static __device__ __forceinline__ ushort f2bf(float f) {
    unsigned int u = __float_as_uint(f);
    u += 0x7FFFu + ((u >> 16) & 1u);   // RNE
    return (ushort)(u >> 16);
}

// ---------------- prep A: NCHW f32 -> NHWC bf16 ----------------
__global__ __launch_bounds__(256) void prep_nhwc(
    const float* __restrict__ in, ushort* __restrict__ nhwc)
{
    __shared__ ushort tile[64][66];   // pad 66 -> conflict-free
    const int t  = threadIdx.x;
    const int b  = blockIdx.x / 144;
    const int s0 = (blockIdx.x % 144) * 64;
    const float* ib = in + (size_t)b * Cn * HW;
    #pragma unroll
    for (int i = 0; i < 16; ++i) {
        const int c = i * 4 + (t >> 6);
        tile[t & 63][c] = f2bf(ib[(size_t)c * HW + s0 + (t & 63)]);
    }
    __syncthreads();
    ushort* ob = nhwc + ((size_t)b * HW + s0) * 64;
    #pragma unroll
    for (int i = 0; i < 16; ++i) {
        const int s = i * 4 + (t >> 6);
        ob[s * 64 + (t & 63)] = tile[s][t & 63];
    }
}

// ---------------- prep B: weight f32 [o][c*9+k] -> bf16 [o][k*64+c] ----------------
__global__ __launch_bounds__(256) void prep_w(
    const float* __restrict__ w, ushort* __restrict__ wb)
{
    const int e = blockIdx.x * 256 + threadIdx.x;
    if (e < Con * CK) {
        const int o  = e / CK;
        const int ck = e - o * CK;     // k*64 + c
        const int k  = ck >> 6;
        const int c  = ck & 63;
        wb[e] = f2bf(w[(size_t)o * CK + c * Kk + k]);
    }
}

// ---------------- main: sample + MFMA GEMM ----------------
__global__ __launch_bounds__(256, 4) void dcnv2_main(
    const ushort* __restrict__ nhwc,   // [B][HW][64] bf16
    const ushort* __restrict__ wb,     // [64][576] bf16, ck = k*64+c
    const float*  __restrict__ offset,
    const float*  __restrict__ mask,
    const float*  __restrict__ bias,
    float* __restrict__ out)
{
    __shared__ float4 s_w[PIX * Kk];
    __shared__ int4   s_a[PIX * Kk];
    __shared__ float  s_bias[Con];
    __shared__ __align__(16) ushort s_samp[PIX][SROW];

    const int t    = threadIdx.x;
    const int lane = t & 63;
    const int wv   = t >> 6;                 // wave id 0..3 -> o-strip
    const int orig = blockIdx.x;
    const int blk  = (orig & 7) * 288 + (orig >> 3);   // XCD-bijective swizzle (2304=8*288)
    const int b    = blk / NTILE;
    const int tile = blk % NTILE;
    const int pix0 = tile * PIX;
    const int ho   = pix0 / Wn;
    const int wo0  = pix0 % Wn;

    // ---- A preload: wave wv owns o in [wv*16, wv*16+16), 18 K-steps of 32 ----
    const int o_m = lane & 15;
    const int kq  = lane >> 4;               // 0..3
    bf16x8 afrag[18];
    {
        const ushort* wrow = wb + (size_t)(wv * 16 + o_m) * CK + kq * 8;
        #pragma unroll
        for (int s = 0; s < 18; ++s)
            afrag[s] = *(const bf16x8*)(wrow + s * 32);
    }

    // ---- phase 0: bilinear params for 144 (pixel,k) pairs ----
    if (t < PIX * Kk) {
        const int p  = t / Kk;
        const int k  = t - p * Kk;
        const int wo = wo0 + p;
        const int sp = ho * Wn + wo;
        const float dy = offset[(size_t)(b * 2 * Kk + 2 * k    ) * HW + sp];
        const float dx = offset[(size_t)(b * 2 * Kk + 2 * k + 1) * HW + sp];
        const float m  = mask  [(size_t)(b * Kk + k) * HW + sp];
        const float py = dy + (float)(k / 3) + (float)(ho - 1);
        const float px = dx + (float)(k % 3) + (float)(wo - 1);
        const float fy = floorf(py), fx = floorf(px);
        const int iy0 = (int)fy, ix0 = (int)fx;
        const int iy1 = iy0 + 1, ix1 = ix0 + 1;
        const float wy = py - fy, wx = px - fx;
        const float vy0 = (iy0 >= 0 && iy0 < Hn) ? 1.f : 0.f;
        const float vy1 = (iy1 >= 0 && iy1 < Hn) ? 1.f : 0.f;
        const float vx0 = (ix0 >= 0 && ix0 < Wn) ? 1.f : 0.f;
        const float vx1 = (ix1 >= 0 && ix1 < Wn) ? 1.f : 0.f;
        const int cy0 = min(max(iy0, 0), Hn - 1), cy1 = min(max(iy1, 0), Hn - 1);
        const int cx0 = min(max(ix0, 0), Wn - 1), cx1 = min(max(ix1, 0), Wn - 1);
        s_w[t] = make_float4(m * (1.f - wy) * (1.f - wx) * vy0 * vx0,
                             m * (1.f - wy) * wx         * vy0 * vx1,
                             m * wy         * (1.f - wx) * vy1 * vx0,
                             m * wy         * wx         * vy1 * vx1);
        s_a[t] = make_int4((cy0 * Wn + cx0) * 64, (cy0 * Wn + cx1) * 64,
                           (cy1 * Wn + cx0) * 64, (cy1 * Wn + cx1) * 64);
    }
    if (t >= 192) s_bias[t & 63] = bias[t & 63];
    __syncthreads();

    // ---- phase 1: sample -> s_samp[p][k*64+c] bf16 ----
    {
        const ushort* nb = nhwc + (size_t)b * HW * 64;
        const int p1 = t >> 4;       // pixel 0..15
        const int c4 = t & 15;       // channel group, ch = 4*c4
        #pragma unroll
        for (int k = 0; k < Kk; ++k) {
            const int pk = p1 * Kk + k;
            const float4 wg = s_w[pk];
            const int4   ad = s_a[pk];
            const ushort4 r00 = *(const ushort4*)(nb + ad.x + 4 * c4);
            const ushort4 r01 = *(const ushort4*)(nb + ad.y + 4 * c4);
            const ushort4 r10 = *(const ushort4*)(nb + ad.z + 4 * c4);
            const ushort4 r11 = *(const ushort4*)(nb + ad.w + 4 * c4);
            const float a0 = wg.x*bf2f(r00.x) + wg.y*bf2f(r01.x) + wg.z*bf2f(r10.x) + wg.w*bf2f(r11.x);
            const float a1 = wg.x*bf2f(r00.y) + wg.y*bf2f(r01.y) + wg.z*bf2f(r10.y) + wg.w*bf2f(r11.y);
            const float a2 = wg.x*bf2f(r00.z) + wg.y*bf2f(r01.z) + wg.z*bf2f(r10.z) + wg.w*bf2f(r11.z);
            const float a3 = wg.x*bf2f(r00.w) + wg.y*bf2f(r01.w) + wg.z*bf2f(r10.w) + wg.w*bf2f(r11.w);
            ushort4 pk4;
            pk4.x = f2bf(a0); pk4.y = f2bf(a1); pk4.z = f2bf(a2); pk4.w = f2bf(a3);
            *(ushort4*)&s_samp[p1][k * 64 + 4 * c4] = pk4;
        }
    }
    __syncthreads();

    // ---- phase 2: MFMA GEMM, wave tile [16o x 16p], K = 576 = 18*32 ----
    f32x4 acc = {0.f, 0.f, 0.f, 0.f};
    {
        const int pB = lane & 15;
        const ushort* brow = &s_samp[pB][kq * 8];
        #pragma unroll
        for (int s = 0; s < 18; ++s) {
            const bf16x8 bfrag = *(const bf16x8*)(brow + s * 32);
            acc = __builtin_amdgcn_mfma_f32_16x16x32_bf16(afrag[s], bfrag, acc, 0, 0, 0);
        }
    }

    // ---- epilogue: D row = (lane>>4)*4 + r, col = lane&15 ----
    {
        const int p    = lane & 15;
        const int orow = wv * 16 + (lane >> 4) * 4;
        #pragma unroll
        for (int r = 0; r < 4; ++r) {
            out[((size_t)b * Con + orow + r) * HW + pix0 + p] = acc[r] + s_bias[orow + r];
        }
    }
}

// ---------------- fallback (round-1 fp32 kernel, used if ws too small) ----------------
__global__ __launch_bounds__(256) void dcnv2_fused(
    const float* __restrict__ input, const float* __restrict__ offset,
    const float* __restrict__ mask, const float* __restrict__ weight,
    const float* __restrict__ bias, float* __restrict__ out)
{
    __shared__ float s_w[PIX*Kk][4];
    __shared__ int   s_a[PIX*Kk][4];
    __shared__ float s_samp[CK*PIX];
    const int t = threadIdx.x, blk = blockIdx.x;
    const int b = blk / NTILE, tile = blk % NTILE;
    const int pix0 = tile * PIX, ho = pix0 / Wn, wo0 = pix0 % Wn;
    if (t < PIX*Kk) {
        const int p = t / Kk, k = t - p*Kk, wo = wo0 + p, sp = ho*Wn + wo;
        const float dy = offset[(size_t)(b*2*Kk + 2*k)*HW + sp];
        const float dx = offset[(size_t)(b*2*Kk + 2*k + 1)*HW + sp];
        const float m  = mask[(size_t)(b*Kk + k)*HW + sp];
        const float py = dy + (float)(k/3) + (float)(ho - 1);
        const float px = dx + (float)(k%3) + (float)(wo - 1);
        const float fy = floorf(py), fx = floorf(px);
        const int iy0 = (int)fy, ix0 = (int)fx, iy1 = iy0+1, ix1 = ix0+1;
        const float wy = py - fy, wx = px - fx;
        const float vy0 = (iy0>=0 && iy0<Hn)?1.f:0.f, vy1 = (iy1>=0 && iy1<Hn)?1.f:0.f;
        const float vx0 = (ix0>=0 && ix0<Wn)?1.f:0.f, vx1 = (ix1>=0 && ix1<Wn)?1.f:0.f;
        const int cy0 = min(max(iy0,0),Hn-1), cy1 = min(max(iy1,0),Hn-1);
        const int cx0 = min(max(ix0,0),Wn-1), cx1 = min(max(ix1,0),Wn-1);
        s_w[t][0]=m*(1.f-wy)*(1.f-wx)*vy0*vx0; s_w[t][1]=m*(1.f-wy)*wx*vy0*vx1;
        s_w[t][2]=m*wy*(1.f-wx)*vy1*vx0;       s_w[t][3]=m*wy*wx*vy1*vx1;
        s_a[t][0]=cy0*Wn+cx0; s_a[t][1]=cy0*Wn+cx1; s_a[t][2]=cy1*Wn+cx0; s_a[t][3]=cy1*Wn+cx1;
    }
    __syncthreads();
    {
        const float* inb = input + (size_t)b*Cn*HW;
        #pragma unroll 4
        for (int e = t; e < CK*PIX; e += 256) {
            const int ck = e >> 4, p = e & 15, c = ck / 9, k = ck - c*9, pk = p*Kk + k;
            const float* ic = inb + (size_t)c*HW;
            s_samp[ck*PIX + p] = s_w[pk][0]*ic[s_a[pk][0]] + s_w[pk][1]*ic[s_a[pk][1]]
                               + s_w[pk][2]*ic[s_a[pk][2]] + s_w[pk][3]*ic[s_a[pk][3]];
        }
    }
    __syncthreads();
    const int o = t & 63, pg = t >> 6;
    const float4* wrow = (const float4*)(weight + (size_t)o*CK);
    float ax=0.f, ay=0.f, az=0.f, aw=0.f;
    #pragma unroll 4
    for (int q = 0; q < CK/4; ++q) {
        const float4 wv = wrow[q];
        const float4 s0 = *(const float4*)&s_samp[(4*q+0)*PIX + pg*4];
        const float4 s1 = *(const float4*)&s_samp[(4*q+1)*PIX + pg*4];
        const float4 s2 = *(const float4*)&s_samp[(4*q+2)*PIX + pg*4];
        const float4 s3 = *(const float4*)&s_samp[(4*q+3)*PIX + pg*4];
        ax += wv.x*s0.x + wv.y*s1.x + wv.z*s2.x + wv.w*s3.x;
        ay += wv.x*s0.y + wv.y*s1.y + wv.z*s2.y + wv.w*s3.y;
        az += wv.x*s0.z + wv.y*s1.z + wv.z*s2.z + wv.w*s3.z;
        aw += wv.x*s0.w + wv.y*s1.w + wv.z*s2.w + wv.w*s3.w;
    }
    const float bo = bias[o];
    float* op = out + (size_t)(b*Con + o)*HW + pix0 + pg*4;
    op[0]=ax+bo; op[1]=ay+bo; op[2]=az+bo; op[3]=aw+bo;
}

extern "C" void kernel_launch(void* const* d_in, const int* in_sizes, int n_in,
                              void* d_out, int out_size, void* d_ws, size_t ws_size,
                              hipStream_t stream) {
    const float* input  = (const float*)d_in[0];
    const float* offset = (const float*)d_in[1];
    const float* mask   = (const float*)d_in[2];
    const float* weight = (const float*)d_in[3];
    const float* bias   = (const float*)d_in[4];
    float* out = (float*)d_out;

    const size_t nhwc_bytes = (size_t)Bn * HW * 64 * 2;      // 4,718,592
    const size_t wb_bytes   = (size_t)Con * CK * 2;          // 73,728
    if (ws_size >= nhwc_bytes + wb_bytes) {
        ushort* nhwc = (ushort*)d_ws;
        ushort* wbuf = (ushort*)((char*)d_ws + nhwc_bytes);
        hipLaunchKernelGGL(prep_nhwc, dim3(Bn * 144), dim3(256), 0, stream, input, nhwc);
        hipLaunchKernelGGL(prep_w,    dim3(144),      dim3(256), 0, stream, weight, wbuf);
        hipLaunchKernelGGL(dcnv2_main, dim3(Bn * NTILE), dim3(256), 0, stream,
                           nhwc, wbuf, offset, mask, bias, out);
    } else {
        hipLaunchKernelGGL(dcnv2_fused, dim3(Bn * NTILE), dim3(256), 0, stream,
                           input, offset, mask, weight, bias, out);
    }
}

// Round 3
// 43.699 us; speedup vs baseline: 4.4584x; 1.0425x over previous
//
#include <hip/hip_runtime.h>

#define Bn  4
#define Cn  64
#define Hn  96
#define Wn  96
#define Con 64
#define Kk  9
#define HW  (Hn*Wn)     // 9216
#define PIX 16
#define CK  (Cn*Kk)     // 576
#define NTILE (HW/PIX)  // 576
#define SROW 584        // samp row stride in bf16 elems

typedef __attribute__((ext_vector_type(8))) short bf16x8;
typedef __attribute__((ext_vector_type(4))) float f32x4;

static __device__ __forceinline__ float bf2f(ushort u) {
    return __uint_as_float(((unsigned int)u) << 16);
}
static __device__ __forceinline__ ushort f2bf(float f) {
    unsigned int u = __float_as_uint(f);
    u += 0x7FFFu + ((u >> 16) & 1u);   // RNE
    return (ushort)(u >> 16);
}

// ---------------- prep A: NCHW f32 -> NHWC bf16 ----------------
__global__ __launch_bounds__(256) void prep_nhwc(
    const float* __restrict__ in, ushort* __restrict__ nhwc)
{
    __shared__ ushort tile[64][66];
    const int t  = threadIdx.x;
    const int b  = blockIdx.x / 144;
    const int s0 = (blockIdx.x % 144) * 64;
    const float* ib = in + (size_t)b * Cn * HW;
    #pragma unroll
    for (int i = 0; i < 16; ++i) {
        const int c = i * 4 + (t >> 6);
        tile[t & 63][c] = f2bf(ib[(size_t)c * HW + s0 + (t & 63)]);
    }
    __syncthreads();
    ushort* ob = nhwc + ((size_t)b * HW + s0) * 64;
    #pragma unroll
    for (int i = 0; i < 16; ++i) {
        const int s = i * 4 + (t >> 6);
        ob[s * 64 + (t & 63)] = tile[s][t & 63];
    }
}

// ---------------- prep B: weight f32 [o][c*9+k] -> bf16 [o][k*64+c] ----------------
__global__ __launch_bounds__(256) void prep_w(
    const float* __restrict__ w, ushort* __restrict__ wb)
{
    const int e = blockIdx.x * 256 + threadIdx.x;
    if (e < Con * CK) {
        const int o  = e / CK;
        const int ck = e - o * CK;
        const int k  = ck >> 6;
        const int c  = ck & 63;
        wb[e] = f2bf(w[(size_t)o * CK + c * Kk + k]);
    }
}

// ---------------- main: sample + MFMA GEMM ----------------
__global__ __launch_bounds__(256, 4) void dcnv2_main(
    const ushort* __restrict__ nhwc,   // [B][HW][64] bf16
    const ushort* __restrict__ wb,     // [64][576] bf16, ck = k*64+c
    const float*  __restrict__ offset,
    const float*  __restrict__ mask,
    const float*  __restrict__ bias,
    float* __restrict__ out)
{
    __shared__ float4 s_w[PIX * Kk];
    __shared__ int4   s_a[PIX * Kk];
    __shared__ float  s_bias[Con];
    __shared__ __align__(16) ushort s_samp[PIX][SROW];

    const int t    = threadIdx.x;
    const int lane = t & 63;
    const int wv   = t >> 6;
    const int orig = blockIdx.x;
    const int blk  = (orig & 7) * 288 + (orig >> 3);   // XCD-bijective (2304=8*288)
    const int b    = blk / NTILE;
    const int tile = blk % NTILE;
    const int pix0 = tile * PIX;
    const int ho   = pix0 / Wn;
    const int wo0  = pix0 % Wn;

    // ---- prefetch phase-0 inputs FIRST (longest dependency chain) ----
    float p_dy = 0.f, p_dx = 0.f, p_m = 0.f, p_bias = 0.f;
    const int p0 = t / Kk;
    const int k0 = t - p0 * Kk;
    if (t < PIX * Kk) {
        const int sp = ho * Wn + wo0 + p0;
        p_dy = offset[(size_t)(b * 2 * Kk + 2 * k0    ) * HW + sp];
        p_dx = offset[(size_t)(b * 2 * Kk + 2 * k0 + 1) * HW + sp];
        p_m  = mask  [(size_t)(b * Kk + k0) * HW + sp];
    } else if (t >= 192) {
        p_bias = bias[t & 63];
    }

    // ---- A preload: wave wv owns o in [wv*16, wv*16+16), pinned in VGPRs ----
    const int o_m = lane & 15;
    const int kq  = lane >> 4;
    f32x4 afrag[18];
    {
        const ushort* wrow = wb + (size_t)(wv * 16 + o_m) * CK + kq * 8;
        #pragma unroll
        for (int s = 0; s < 18; ++s)
            afrag[s] = *(const f32x4*)(wrow + s * 32);
        #pragma unroll
        for (int s = 0; s < 18; ++s)
            asm volatile("" : "+v"(afrag[s]));   // force materialization, block remat/sink
    }

    // ---- phase 0: bilinear params ----
    if (t < PIX * Kk) {
        const int wo = wo0 + p0;
        const float py = p_dy + (float)(k0 / 3) + (float)(ho - 1);
        const float px = p_dx + (float)(k0 % 3) + (float)(wo - 1);
        const float fy = floorf(py), fx = floorf(px);
        const int iy0 = (int)fy, ix0 = (int)fx;
        const int iy1 = iy0 + 1, ix1 = ix0 + 1;
        const float wy = py - fy, wx = px - fx;
        const float vy0 = (iy0 >= 0 && iy0 < Hn) ? 1.f : 0.f;
        const float vy1 = (iy1 >= 0 && iy1 < Hn) ? 1.f : 0.f;
        const float vx0 = (ix0 >= 0 && ix0 < Wn) ? 1.f : 0.f;
        const float vx1 = (ix1 >= 0 && ix1 < Wn) ? 1.f : 0.f;
        const int cy0 = min(max(iy0, 0), Hn - 1), cy1 = min(max(iy1, 0), Hn - 1);
        const int cx0 = min(max(ix0, 0), Wn - 1), cx1 = min(max(ix1, 0), Wn - 1);
        s_w[t] = make_float4(p_m * (1.f - wy) * (1.f - wx) * vy0 * vx0,
                             p_m * (1.f - wy) * wx         * vy0 * vx1,
                             p_m * wy         * (1.f - wx) * vy1 * vx0,
                             p_m * wy         * wx         * vy1 * vx1);
        s_a[t] = make_int4((cy0 * Wn + cx0) * 64, (cy0 * Wn + cx1) * 64,
                           (cy1 * Wn + cx0) * 64, (cy1 * Wn + cx1) * 64);
    } else if (t >= 192) {
        s_bias[t & 63] = p_bias;
    }
    __syncthreads();

    // ---- phase 1: sample -> s_samp[p][k*64+c] bf16 ----
    {
        const ushort* nb = nhwc + (size_t)b * HW * 64;
        const int p1 = t >> 4;
        const int c4 = t & 15;
        #pragma unroll
        for (int k = 0; k < Kk; ++k) {
            const int pk = p1 * Kk + k;
            const float4 wg = s_w[pk];
            const int4   ad = s_a[pk];
            const ushort4 r00 = *(const ushort4*)(nb + ad.x + 4 * c4);
            const ushort4 r01 = *(const ushort4*)(nb + ad.y + 4 * c4);
            const ushort4 r10 = *(const ushort4*)(nb + ad.z + 4 * c4);
            const ushort4 r11 = *(const ushort4*)(nb + ad.w + 4 * c4);
            const float a0 = wg.x*bf2f(r00.x) + wg.y*bf2f(r01.x) + wg.z*bf2f(r10.x) + wg.w*bf2f(r11.x);
            const float a1 = wg.x*bf2f(r00.y) + wg.y*bf2f(r01.y) + wg.z*bf2f(r10.y) + wg.w*bf2f(r11.y);
            const float a2 = wg.x*bf2f(r00.z) + wg.y*bf2f(r01.z) + wg.z*bf2f(r10.z) + wg.w*bf2f(r11.z);
            const float a3 = wg.x*bf2f(r00.w) + wg.y*bf2f(r01.w) + wg.z*bf2f(r10.w) + wg.w*bf2f(r11.w);
            ushort4 pk4;
            pk4.x = f2bf(a0); pk4.y = f2bf(a1); pk4.z = f2bf(a2); pk4.w = f2bf(a3);
            *(ushort4*)&s_samp[p1][k * 64 + 4 * c4] = pk4;
        }
    }
    __syncthreads();

    // ---- phase 2: MFMA GEMM, wave tile [16o x 16p], K = 576 = 18*32 ----
    f32x4 acc = {0.f, 0.f, 0.f, 0.f};
    {
        const int pB = lane & 15;
        const ushort* brow = &s_samp[pB][kq * 8];
        #pragma unroll
        for (int s = 0; s < 18; ++s) {
            const bf16x8 bfrag = *(const bf16x8*)(brow + s * 32);
            acc = __builtin_amdgcn_mfma_f32_16x16x32_bf16(
                __builtin_bit_cast(bf16x8, afrag[s]), bfrag, acc, 0, 0, 0);
        }
    }

    // ---- epilogue ----
    {
        const int p    = lane & 15;
        const int orow = wv * 16 + (lane >> 4) * 4;
        #pragma unroll
        for (int r = 0; r < 4; ++r) {
            out[((size_t)b * Con + orow + r) * HW + pix0 + p] = acc[r] + s_bias[orow + r];
        }
    }
}

// ---------------- fallback (round-1 fp32 kernel, used if ws too small) ----------------
__global__ __launch_bounds__(256) void dcnv2_fused(
    const float* __restrict__ input, const float* __restrict__ offset,
    const float* __restrict__ mask, const float* __restrict__ weight,
    const float* __restrict__ bias, float* __restrict__ out)
{
    __shared__ float s_w[PIX*Kk][4];
    __shared__ int   s_a[PIX*Kk][4];
    __shared__ float s_samp[CK*PIX];
    const int t = threadIdx.x, blk = blockIdx.x;
    const int b = blk / NTILE, tile = blk % NTILE;
    const int pix0 = tile * PIX, ho = pix0 / Wn, wo0 = pix0 % Wn;
    if (t < PIX*Kk) {
        const int p = t / Kk, k = t - p*Kk, wo = wo0 + p, sp = ho*Wn + wo;
        const float dy = offset[(size_t)(b*2*Kk + 2*k)*HW + sp];
        const float dx = offset[(size_t)(b*2*Kk + 2*k + 1)*HW + sp];
        const float m  = mask[(size_t)(b*Kk + k)*HW + sp];
        const float py = dy + (float)(k/3) + (float)(ho - 1);
        const float px = dx + (float)(k%3) + (float)(wo - 1);
        const float fy = floorf(py), fx = floorf(px);
        const int iy0 = (int)fy, ix0 = (int)fx, iy1 = iy0+1, ix1 = ix0+1;
        const float wy = py - fy, wx = px - fx;
        const float vy0 = (iy0>=0 && iy0<Hn)?1.f:0.f, vy1 = (iy1>=0 && iy1<Hn)?1.f:0.f;
        const float vx0 = (ix0>=0 && ix0<Wn)?1.f:0.f, vx1 = (ix1>=0 && ix1<Wn)?1.f:0.f;
        const int cy0 = min(max(iy0,0),Hn-1), cy1 = min(max(iy1,0),Hn-1);
        const int cx0 = min(max(ix0,0),Wn-1), cx1 = min(max(ix1,0),Wn-1);
        s_w[t][0]=m*(1.f-wy)*(1.f-wx)*vy0*vx0; s_w[t][1]=m*(1.f-wy)*wx*vy0*vx1;
        s_w[t][2]=m*wy*(1.f-wx)*vy1*vx0;       s_w[t][3]=m*wy*wx*vy1*vx1;
        s_a[t][0]=cy0*Wn+cx0; s_a[t][1]=cy0*Wn+cx1; s_a[t][2]=cy1*Wn+cx0; s_a[t][3]=cy1*Wn+cx1;
    }
    __syncthreads();
    {
        const float* inb = input + (size_t)b*Cn*HW;
        #pragma unroll 4
        for (int e = t; e < CK*PIX; e += 256) {
            const int ck = e >> 4, p = e & 15, c = ck / 9, k = ck - c*9, pk = p*Kk + k;
            const float* ic = inb + (size_t)c*HW;
            s_samp[ck*PIX + p] = s_w[pk][0]*ic[s_a[pk][0]] + s_w[pk][1]*ic[s_a[pk][1]]
                               + s_w[pk][2]*ic[s_a[pk][2]] + s_w[pk][3]*ic[s_a[pk][3]];
        }
    }
    __syncthreads();
    const int o = t & 63, pg = t >> 6;
    const float4* wrow = (const float4*)(weight + (size_t)o*CK);
    float ax=0.f, ay=0.f, az=0.f, aw=0.f;
    #pragma unroll 4
    for (int q = 0; q < CK/4; ++q) {
        const float4 wv = wrow[q];
        const float4 s0 = *(const float4*)&s_samp[(4*q+0)*PIX + pg*4];
        const float4 s1 = *(const float4*)&s_samp[(4*q+1)*PIX + pg*4];
        const float4 s2 = *(const float4*)&s_samp[(4*q+2)*PIX + pg*4];
        const float4 s3 = *(const float4*)&s_samp[(4*q+3)*PIX + pg*4];
        ax += wv.x*s0.x + wv.y*s1.x + wv.z*s2.x + wv.w*s3.x;
        ay += wv.x*s0.y + wv.y*s1.y + wv.z*s2.y + wv.w*s3.y;
        az += wv.x*s0.z + wv.y*s1.z + wv.z*s2.z + wv.w*s3.z;
        aw += wv.x*s0.w + wv.y*s1.w + wv.z*s2.w + wv.w*s3.w;
    }
    const float bo = bias[o];
    float* op = out + (size_t)(b*Con + o)*HW + pix0 + pg*4;
    op[0]=ax+bo; op[1]=ay+bo; op[2]=az+bo; op[3]=aw+bo;
}

extern "C" void kernel_launch(void* const* d_in, const int* in_sizes, int n_in,
                              void* d_out, int out_size, void* d_ws, size_t ws_size,
                              hipStream_t stream) {
    const float* input  = (const float*)d_in[0];
    const float* offset = (const float*)d_in[1];
    const float* mask   = (const float*)d_in[2];
    const float* weight = (const float*)d_in[3];
    const float* bias   = (const float*)d_in[4];
    float* out = (float*)d_out;

    const size_t nhwc_bytes = (size_t)Bn * HW * 64 * 2;
    const size_t wb_bytes   = (size_t)Con * CK * 2;
    if (ws_size >= nhwc_bytes + wb_bytes) {
        ushort* nhwc = (ushort*)d_ws;
        ushort* wbuf = (ushort*)((char*)d_ws + nhwc_bytes);
        hipLaunchKernelGGL(prep_nhwc, dim3(Bn * 144), dim3(256), 0, stream, input, nhwc);
        hipLaunchKernelGGL(prep_w,    dim3(144),      dim3(256), 0, stream, weight, wbuf);
        hipLaunchKernelGGL(dcnv2_main, dim3(Bn * NTILE), dim3(256), 0, stream,
                           nhwc, wbuf, offset, mask, bias, out);
    } else {
        hipLaunchKernelGGL(dcnv2_fused, dim3(Bn * NTILE), dim3(256), 0, stream,
                           input, offset, mask, weight, bias, out);
    }
}